// Round 6
// baseline (261.112 us; speedup 1.0000x reference)
//
#include <hip/hip_runtime.h>

// LSTM (B=2048, T=168, I=6, H=128) + FC(128->64, PReLU) + FC(64->1, PReLU).
// V6: MFMA bf16 3-term split with K-EXPANSION (no cross-lane fold).
// 256 blocks x 512 threads (8 waves); block owns 8 batch rows for all 168 steps.
// A-tile slots (K''=288): [0,128)=h_hi, [128,256)=h_lo, [256,262)=x_hi,
// [262,268)=x_lo, 268=1.0 (bias col), [269,288)=0.  Physical LDS A = 8 rows;
// lanes l15>=8 broadcast-read row l15-8, so D rows 8-15 duplicate batch rows
// 0-7 -> all 64 lanes do the pointwise with NO shfl fold.
// B planes (register-resident, 160 VGPR): P1 = W_hh_hi over kk0-3, mirrored
// for kk4-7 (pairs h_lo -> al*bh), x/bias at kk8; P2 = W_hh_lo over kk0-3
// (ah*bl) + x/bias-lo at kk8.  56 MFMA/wave/step, 1 barrier/step.

typedef __attribute__((ext_vector_type(8))) short short8;
typedef __attribute__((ext_vector_type(4))) float f32x4;

#define BT 512
#define TS 168
#define HID 128
#define AROW 320     // A-array row stride in ushorts (640 B; rows land on bank 0, XOR spreads)
#define NNT 4        // 4 gate tiles per wave

__device__ __forceinline__ ushort bf_hi(float v) {
    return (ushort)(__float_as_uint(v) >> 16);
}
__device__ __forceinline__ ushort bf_lo(float v) {
    unsigned h = __float_as_uint(v) & 0xFFFF0000u;
    float l = v - __uint_as_float(h);
    return (ushort)(__float_as_uint(l) >> 16);
}
__device__ __forceinline__ float sigm_f(float x) {
    return __fdividef(1.f, 1.f + __expf(-x));
}
__device__ __forceinline__ float tanh_f(float x) {
    return 1.f - __fdividef(2.f, __expf(2.f * x) + 1.f);
}

__global__ __launch_bounds__(BT, 2) void lstm_mfma6_kernel(
    const float* __restrict__ s_inp,   // [2048,168,5]
    const float* __restrict__ flow_x,  // [2048,168,1]
    const float* __restrict__ W_ih,    // [512,6]
    const float* __restrict__ W_hh,    // [512,128]
    const float* __restrict__ b_ih,    // [512]
    const float* __restrict__ b_hh,    // [512]
    const float* __restrict__ W1,      // [64,128]
    const float* __restrict__ b1,      // [64]
    const float* __restrict__ a1p,     // [1]
    const float* __restrict__ W2,      // [1,64]
    const float* __restrict__ b2,      // [1]
    const float* __restrict__ a2p,     // [1]
    float* __restrict__ out)           // [2048]
{
    __shared__ float xs[8][TS][6];                    // 32256 B
    __shared__ __align__(16) ushort hA[8 * AROW];     // 5120 B
    __shared__ float y1s[8][64];                      // 2048 B

    const int t = threadIdx.x;
    const int w = t >> 6;       // wave 0..7
    const int l = t & 63;
    const int l15 = l & 15;
    const int l4 = l >> 4;      // 0..3
    const int row_base = blockIdx.x * 8;

    // ---- register-resident B fragments ----
    // storage index q: 0-3 <-> kk 0-3 (also reused for kk 4-7), 4 <-> kk 8.
    // lane holds B[slot = kkbase + l4*8 + j][gc = nt*128 + w*16 + l15].
    short8 P1s[5][NNT], P2s[5][NNT];
    #pragma unroll
    for (int nt = 0; nt < NNT; ++nt) {
        const int gc = nt * HID + w * 16 + l15;
        const float bias = b_ih[gc] + b_hh[gc];
        #pragma unroll
        for (int q = 0; q < 4; ++q) {
            #pragma unroll
            for (int j = 0; j < 8; ++j) {
                float v = W_hh[gc * HID + q * 32 + l4 * 8 + j];
                P1s[q][nt][j] = (short)bf_hi(v);
                P2s[q][nt][j] = (short)bf_lo(v);
            }
        }
        #pragma unroll
        for (int j = 0; j < 8; ++j) {
            int u = l4 * 8 + j;   // slot 256+u
            float v = (u < 6)  ? W_ih[gc * 6 + u]
                    : (u < 12) ? W_ih[gc * 6 + (u - 6)]
                    : (u == 12) ? bias : 0.f;
            P1s[4][nt][j] = (short)bf_hi(v);
            P2s[4][nt][j] = (short)bf_lo(v);
        }
    }

    // ---- stage x for this block's 8 rows into LDS (coalesced) ----
    for (int idx = t; idx < 8 * TS * 5; idx += BT) {
        int r = idx / (TS * 5), rem = idx % (TS * 5);
        xs[r][rem / 5][rem % 5] = s_inp[(size_t)row_base * (TS * 5) + idx];
    }
    for (int idx = t; idx < 8 * TS; idx += BT) {
        xs[idx / TS][idx % TS][5] = flow_x[(size_t)row_base * TS + idx];
    }
    // zero A-array
    for (int idx = t; idx < 8 * AROW / 2; idx += BT)
        ((unsigned*)hA)[idx] = 0u;
    __syncthreads();

    // bias column (slot 268) = 1.0 in all 8 rows
    if (t < 8) {
        int byte = (2 * 268) ^ ((t & 7) << 4);
        hA[t * AROW + (byte >> 1)] = 0x3F80;
    }
    // x staging: threads 0-47 write x_hi (slots 256+i), 64-111 write x_lo (262+i)
    const bool xhi = (t < 48);
    const bool xlo = (t >= 64 && t < 112);
    const int xu = xhi ? t : (t - 64);
    const int xr = (xu < 48) ? (xu / 6) : 0;
    const int xi = (xu < 48) ? (xu % 6) : 0;
    const int xslot = xhi ? (256 + xi) : (262 + xi);
    const int xw_idx = xr * AROW + ((((2 * xslot) ^ ((xr & 7) << 4))) >> 1);
    if (xhi | xlo) {
        float v = xs[xr][0][xi];
        hA[xw_idx] = xhi ? bf_hi(v) : bf_lo(v);
    }

    // ---- per-step constants ----
    const int arow = l15 & 7;                       // physical A row (l15>=8 broadcasts)
    const int a_base = arow * AROW;
    const int a_swz = arow << 4;
    const int ch = w * 16 + l15;                    // this lane's channel
    const bool lowhalf = (l < 32);
    const int rbase = (l4 & 1) * 4 + (lowhalf ? 0 : 2);  // lane's 2 rows
    const int row0 = rbase, row1 = rbase + 1;
    const int hw0 = row0 * AROW + ((((2 * ch) ^ (row0 << 4))) >> 1);  // h_hi; +128 = h_lo
    const int hw1 = row1 * AROW + ((((2 * ch) ^ (row1 << 4))) >> 1);

    float c0 = 0.f, c1 = 0.f, h0f = 0.f, h1f = 0.f;

    for (int s = 0; s < TS; ++s) {
        __syncthreads();  // h(s)/x(s) writes visible

        f32x4 acc[NNT];
        #pragma unroll
        for (int nt = 0; nt < NNT; ++nt) acc[nt] = (f32x4){0.f, 0.f, 0.f, 0.f};

        #pragma unroll
        for (int kk = 0; kk < 9; ++kk) {
            const int q = (kk < 4) ? kk : ((kk < 8) ? kk - 4 : 4);
            int off = ((kk * 64 + l4 * 16) ^ a_swz) >> 1;  // ushort units, 16B aligned
            short8 a = *(const short8*)(hA + a_base + off);
            #pragma unroll
            for (int nt = 0; nt < NNT; ++nt)
                acc[nt] = __builtin_amdgcn_mfma_f32_16x16x32_bf16(a, P1s[q][nt], acc[nt], 0, 0, 0);
            if (kk < 4 || kk == 8) {
                #pragma unroll
                for (int nt = 0; nt < NNT; ++nt)
                    acc[nt] = __builtin_amdgcn_mfma_f32_16x16x32_bf16(a, P2s[q][nt], acc[nt], 0, 0, 0);
            }
        }

        // D row d holds batch row (d&7); lane picks its 2 rows directly — no fold
        float gi0 = lowhalf ? acc[0][0] : acc[0][2];
        float gf0 = lowhalf ? acc[1][0] : acc[1][2];
        float gg0 = lowhalf ? acc[2][0] : acc[2][2];
        float go0 = lowhalf ? acc[3][0] : acc[3][2];
        float gi1 = lowhalf ? acc[0][1] : acc[0][3];
        float gf1 = lowhalf ? acc[1][1] : acc[1][3];
        float gg1 = lowhalf ? acc[2][1] : acc[2][3];
        float go1 = lowhalf ? acc[3][1] : acc[3][3];

        {
            float ia = sigm_f(gi0);
            float fa = sigm_f(gf0);
            float ga = tanh_f(gg0);
            float oa = sigm_f(go0);
            c0 = fa * c0 + ia * ga;
            h0f = oa * tanh_f(c0);
        }
        {
            float ia = sigm_f(gi1);
            float fa = sigm_f(gf1);
            float ga = tanh_f(gg1);
            float oa = sigm_f(go1);
            c1 = fa * c1 + ia * ga;
            h1f = oa * tanh_f(c1);
        }

        // write h hi/lo into A slots (hi at slot ch, lo at slot 128+ch = +128 ushorts)
        hA[hw0] = bf_hi(h0f);
        hA[hw0 + 128] = bf_lo(h0f);
        hA[hw1] = bf_hi(h1f);
        hA[hw1 + 128] = bf_lo(h1f);

        // stage x(s+1)
        if ((xhi | xlo) && s + 1 < TS) {
            float v = xs[xr][s + 1][xi];
            hA[xw_idx] = xhi ? bf_hi(v) : bf_lo(v);
        }
    }
    __syncthreads();  // all lanes done with xs

    // ---- FC head ----
    float* hfin = (float*)xs;  // reuse xs as [8][128] f32
    hfin[row0 * HID + ch] = h0f;
    hfin[row1 * HID + ch] = h1f;
    __syncthreads();

    {
        int r = t >> 6, j = t & 63;
        const float4* wrow = (const float4*)(W1 + j * HID);
        const float4* hr = (const float4*)(hfin + r * HID);
        float acc = b1[j];
        #pragma unroll
        for (int q = 0; q < HID / 4; ++q) {
            float4 a = hr[q], b = wrow[q];
            acc += a.x * b.x + a.y * b.y + a.z * b.z + a.w * b.w;
        }
        float av = a1p[0];
        y1s[r][j] = (acc >= 0.f) ? acc : av * acc;
    }
    __syncthreads();

    if (t < 8) {
        const float4* w2 = (const float4*)W2;
        const float4* yr = (const float4*)&y1s[t][0];
        float acc = 0.f;
        #pragma unroll
        for (int q = 0; q < 64 / 4; ++q) {
            float4 a = yr[q], b = w2[q];
            acc += a.x * b.x + a.y * b.y + a.z * b.z + a.w * b.w;
        }
        acc += b2[0];
        float av = a2p[0];
        out[row_base + t] = (acc >= 0.f) ? acc : av * acc;
    }
}

extern "C" void kernel_launch(void* const* d_in, const int* in_sizes, int n_in,
                              void* d_out, int out_size, void* d_ws, size_t ws_size,
                              hipStream_t stream) {
    const float* s_inp  = (const float*)d_in[0];
    const float* flow_x = (const float*)d_in[1];
    const float* W_ih   = (const float*)d_in[2];
    const float* W_hh   = (const float*)d_in[3];
    const float* b_ih   = (const float*)d_in[4];
    const float* b_hh   = (const float*)d_in[5];
    const float* W1     = (const float*)d_in[6];
    const float* b1     = (const float*)d_in[7];
    const float* a1     = (const float*)d_in[8];
    const float* W2     = (const float*)d_in[9];
    const float* b2     = (const float*)d_in[10];
    const float* a2     = (const float*)d_in[11];
    float* out = (float*)d_out;

    dim3 grid(2048 / 8);   // 256 blocks, 8 rows each -> 1 block/CU
    dim3 block(BT);
    lstm_mfma6_kernel<<<grid, block, 0, stream>>>(
        s_inp, flow_x, W_ih, W_hh, b_ih, b_hh, W1, b1, a1, W2, b2, a2, out);
}